// Round 1
// baseline (215.366 us; speedup 1.0000x reference)
//
#include <hip/hip_runtime.h>

#define N_NODES 100000
#define N_FEAT  512
#define N_EDGES 3200000

// ---------------------------------------------------------------------------
// ws layout: [ int deg[N_NODES] | float present[N_FEAT] ]
// ---------------------------------------------------------------------------

__global__ void init_ws_kernel(int* __restrict__ deg, float* __restrict__ present) {
    int i = blockIdx.x * blockDim.x + threadIdx.x;
    if (i < N_NODES) deg[i] = 0;
    if (i < N_FEAT)  present[i] = 0.0f;
}

__global__ void degree_kernel(const int* __restrict__ dst, int* __restrict__ deg) {
    int i = blockIdx.x * blockDim.x + threadIdx.x;
    int stride = gridDim.x * blockDim.x;
    for (; i < N_EDGES; i += stride) {
        atomicAdd(&deg[dst[i]], 1);
    }
}

__global__ void present_kernel(const int* __restrict__ deg, float* __restrict__ present) {
    int i = blockIdx.x * blockDim.x + threadIdx.x;
    if (i < N_NODES) {
        int si = min(deg[i], N_FEAT - 1);
        present[si] = 1.0f;   // benign race: all writers store 1.0f
    }
}

// One float4 per thread-iteration; 128 float4 per node row.
__global__ void quant_kernel(const float4* __restrict__ fea,
                             const int*    __restrict__ deg,
                             const float*  __restrict__ gama,
                             const float*  __restrict__ bit,
                             float4*       __restrict__ out) {
    const long long total  = (long long)N_NODES * (N_FEAT / 4);
    long long i      = (long long)blockIdx.x * blockDim.x + threadIdx.x;
    long long stride = (long long)gridDim.x * blockDim.x;
    for (; i < total; i += stride) {
        int node = (int)(i >> 7);                  // 512/4 = 128 float4 per row
        int si   = min(deg[node], N_FEAT - 1);
        float s  = fabsf(gama[si]);
        float b  = rintf(bit[si]);                 // STE round fwd = round-half-even
        float h  = exp2f(b - 1.0f);
        float qmax = h - 1.0f;
        float qmin = -h;
        float inv  = 1.0f / s;

        float4 v = fea[i];
        float4 r;
        r.x = rintf(fminf(fmaxf(v.x * inv, qmin), qmax)) * s;
        r.y = rintf(fminf(fmaxf(v.y * inv, qmin), qmax)) * s;
        r.z = rintf(fminf(fmaxf(v.z * inv, qmin), qmax)) * s;
        r.w = rintf(fminf(fmaxf(v.w * inv, qmin), qmax)) * s;
        out[i] = r;
    }
}

__global__ void bitsum_kernel(const float* __restrict__ bit,
                              const float* __restrict__ present,
                              float* __restrict__ out_scalar) {
    __shared__ float warp_sums[8];                 // 512 threads = 8 waves
    int t = threadIdx.x;
    float v = bit[t] * present[t];
    // wave-64 shuffle reduce
    for (int off = 32; off >= 1; off >>= 1)
        v += __shfl_down(v, off, 64);
    int wave = t >> 6;
    int lane = t & 63;
    if (lane == 0) warp_sums[wave] = v;
    __syncthreads();
    if (t == 0) {
        float total = 0.0f;
        for (int w = 0; w < 8; ++w) total += warp_sums[w];
        out_scalar[0] = (float)N_FEAT * total / 8.0f / 1024.0f;
    }
}

extern "C" void kernel_launch(void* const* d_in, const int* in_sizes, int n_in,
                              void* d_out, int out_size, void* d_ws, size_t ws_size,
                              hipStream_t stream) {
    const float* fea  = (const float*)d_in[0];
    const int*   ei   = (const int*)d_in[1];
    const float* gama = (const float*)d_in[2];
    const float* bit  = (const float*)d_in[3];

    const int* dst = ei + N_EDGES;                 // edge_index[1] is second row

    int*   deg     = (int*)d_ws;
    float* present = (float*)(deg + N_NODES);

    float* out_fea    = (float*)d_out;
    float* out_scalar = out_fea + (long long)N_NODES * N_FEAT;

    const int BLK = 256;

    // 1. zero deg + present
    {
        int n = N_NODES;                           // covers N_FEAT too
        init_ws_kernel<<<(n + BLK - 1) / BLK, BLK, 0, stream>>>(deg, present);
    }
    // 2. in-degree histogram
    degree_kernel<<<2048, BLK, 0, stream>>>(dst, deg);
    // 3. present mask
    present_kernel<<<(N_NODES + BLK - 1) / BLK, BLK, 0, stream>>>(deg, present);
    // 4. quantize rows
    quant_kernel<<<2048, BLK, 0, stream>>>((const float4*)fea, deg, gama, bit,
                                           (float4*)out_fea);
    // 5. bit_sum scalar
    bitsum_kernel<<<1, 512, 0, stream>>>(bit, present, out_scalar);
}